// Round 1
// baseline (2024.303 us; speedup 1.0000x reference)
//
#include <hip/hip_runtime.h>
#include <hip/hip_bf16.h>

typedef __hip_bfloat16 bf16_t;
typedef __bf16 bf16x8_t __attribute__((ext_vector_type(8)));
typedef float f32x4_t __attribute__((ext_vector_type(4)));

// ---------------- workspace layout (bytes) ----------------
#define OFF_X    ((size_t)0)          // 8192*512 f32      = 16,777,216
#define OFF_CI   ((size_t)16777216)   // 8192*1536 bf16    = 25,165,824  (head_w bf16 aliases here after loop)
#define OFF_H1   ((size_t)41943040)   // 8192*1024 bf16    = 16,777,216
#define OFF_XN   ((size_t)58720256)   // 8192*512 bf16     =  8,388,608
#define OFF_W1B  ((size_t)67108864)   // 1024*1536 bf16    =  3,145,728
#define OFF_W2B  ((size_t)70254592)   // 512*1024 bf16     =  1,048,576
#define OFF_ENT  ((size_t)71303168)   // 8192 f32
#define OFF_CW   ((size_t)71335936)   // 8192 f32
#define OFF_HC   ((size_t)71368704)   // 1024 f32
#define OFF_CC   ((size_t)71372800)   // 512  f32
#define OFF_B1   ((size_t)71374848)   // 1024 f32

__device__ __forceinline__ float gelu_f(float v) {
    return 0.5f * v * (1.0f + erff(v * 0.7071067811865475f));
}

__device__ __forceinline__ void load_lds16(const bf16_t* g, bf16_t* l) {
    __builtin_amdgcn_global_load_lds(
        (const __attribute__((address_space(1))) void*)g,
        (__attribute__((address_space(3))) void*)l, 16, 0, 0);
}

// ---------------- prep: ctc MLP on pooled c_states, fold into bias1 ----------------
__global__ void prep1_kernel(const float* __restrict__ cs, const float* __restrict__ w1,
                             const float* __restrict__ b1, float* __restrict__ hc) {
    int o = blockIdx.x * 256 + threadIdx.x;            // 0..1023
    const float* wr = w1 + (size_t)o * 512;
    float acc = 0.f;
    for (int k = 0; k < 512; k += 4) {
        float4 w4 = *(const float4*)(wr + k);
        float4 a = *(const float4*)(cs + k);
        float4 b = *(const float4*)(cs + 512 + k);
        float4 c = *(const float4*)(cs + 1024 + k);
        float4 d = *(const float4*)(cs + 1536 + k);
        acc += w4.x * (a.x + b.x + c.x + d.x) * 0.25f;
        acc += w4.y * (a.y + b.y + c.y + d.y) * 0.25f;
        acc += w4.z * (a.z + b.z + c.z + d.z) * 0.25f;
        acc += w4.w * (a.w + b.w + c.w + d.w) * 0.25f;
    }
    hc[o] = gelu_f(acc + b1[o]);
}

__global__ void prep2_kernel(const float* __restrict__ hc, const float* __restrict__ w2,
                             const float* __restrict__ b2, float* __restrict__ cc) {
    int o = blockIdx.x * 256 + threadIdx.x;            // 0..511
    const float* wr = w2 + (size_t)o * 1024;
    float acc = 0.f;
    for (int k = 0; k < 1024; ++k) acc += wr[k] * hc[k];
    cc[o] = acc + b2[o];
}

__global__ void prep3_kernel(const float* __restrict__ cc, const float* __restrict__ cn_w1,
                             const float* __restrict__ cn_b1, float* __restrict__ bias1) {
    int o = blockIdx.x * 256 + threadIdx.x;            // 0..1023
    const float* wr = cn_w1 + (size_t)o * 2048 + 1536;
    float acc = 0.f;
    for (int k = 0; k < 512; ++k) acc += wr[k] * cc[k];
    bias1[o] = acc + cn_b1[o];
}

// ---------------- embed + pos ----------------
__global__ void embed_kernel(const int* __restrict__ tokens, const float* __restrict__ ew,
                             const float* __restrict__ pw, float* __restrict__ x) {
    int idx = blockIdx.x * 256 + threadIdx.x;          // quad id, total 8192*128
    int d4 = idx & 127;
    int bt = idx >> 7;
    int t = bt & 1023;
    int tok = tokens[bt];
    float4 e = ((const float4*)(ew + (size_t)tok * 512))[d4];
    float4 p = ((const float4*)(pw + (size_t)t * 512))[d4];
    float4 o = make_float4(e.x + p.x, e.y + p.y, e.z + p.z, e.w + p.w);
    ((float4*)x)[idx] = o;
}

// ---------------- build ci = bf16([x, roll+1, roll-1]) ----------------
__global__ void ci_kernel(const float* __restrict__ x, bf16_t* __restrict__ ci) {
    int idx = blockIdx.x * 256 + threadIdx.x;          // quad id, total 8192*384
    int c4 = idx % 384;
    int bt = idx / 384;
    int t = bt & 1023, b = bt >> 10;
    int seg = c4 >> 7;
    int d4 = c4 & 127;
    int st = (seg == 0) ? t : ((seg == 1) ? ((t + 1023) & 1023) : ((t + 1) & 1023));
    float4 v = ((const float4*)(x + ((size_t)((b << 10) | st)) * 512))[d4];
    __hip_bfloat162 p0, p1;
    p0.x = __float2bfloat16(v.x); p0.y = __float2bfloat16(v.y);
    p1.x = __float2bfloat16(v.z); p1.y = __float2bfloat16(v.w);
    ((__hip_bfloat162*)ci)[idx * 2]     = p0;
    ((__hip_bfloat162*)ci)[idx * 2 + 1] = p1;
}

// ---------------- f32 -> bf16 converts ----------------
__global__ void cvt_kernel(const float* __restrict__ src, bf16_t* __restrict__ dst) {
    int idx = blockIdx.x * 256 + threadIdx.x;          // quad id, grid sized exactly
    float4 v = ((const float4*)src)[idx];
    __hip_bfloat162 p0, p1;
    p0.x = __float2bfloat16(v.x); p0.y = __float2bfloat16(v.y);
    p1.x = __float2bfloat16(v.z); p1.y = __float2bfloat16(v.w);
    ((__hip_bfloat162*)dst)[idx * 2]     = p0;
    ((__hip_bfloat162*)dst)[idx * 2 + 1] = p1;
}

__global__ void cvt_w1_kernel(const float* __restrict__ w1, bf16_t* __restrict__ dst) {
    int idx = blockIdx.x * 256 + threadIdx.x;          // quad id, total 1024*384
    int k4 = idx % 384;
    int o = idx / 384;
    float4 v = ((const float4*)(w1 + (size_t)o * 2048))[k4];
    __hip_bfloat162 p0, p1;
    p0.x = __float2bfloat16(v.x); p0.y = __float2bfloat16(v.y);
    p1.x = __float2bfloat16(v.z); p1.y = __float2bfloat16(v.w);
    ((__hip_bfloat162*)dst)[idx * 2]     = p0;
    ((__hip_bfloat162*)dst)[idx * 2 + 1] = p1;
}

// ---------------- entropy MLP: one wave per token ----------------
__global__ void entropy_kernel(const float* __restrict__ x, const float* __restrict__ w1,
                               const float* __restrict__ b1, const float* __restrict__ w2,
                               const float* __restrict__ b2, float* __restrict__ ent) {
    int token = blockIdx.x * 4 + (threadIdx.x >> 6);
    int l = threadIdx.x & 63;
    const float* xr = x + (size_t)token * 512;
    const float* wr = w1 + (size_t)l * 512;
    float acc = 0.f;
    #pragma unroll 4
    for (int k4 = 0; k4 < 128; ++k4) {
        float4 xv = ((const float4*)xr)[k4];
        float4 wv = ((const float4*)wr)[k4];
        acc += xv.x * wv.x + xv.y * wv.y + xv.z * wv.z + xv.w * wv.w;
    }
    float c = gelu_f(acc + b1[l]) * w2[l];
    #pragma unroll
    for (int o = 32; o; o >>= 1) c += __shfl_xor(c, o);
    if (l == 0) ent[token] = c + b2[0];
}

// ---------------- softmax over T (per batch) ----------------
__global__ void softmax_kernel(const float* __restrict__ ent, const float* __restrict__ btp,
                               float stepf, float* __restrict__ cw) {
    __shared__ float red[16];
    __shared__ float bc[2];
    int b = blockIdx.x, t = threadIdx.x;               // 1024 threads
    float bt = btp[0];
    float sp = (bt > 20.0f) ? bt : log1pf(expf(bt));
    float inv = -1.0f / (sp * stepf);
    float v = ent[b * 1024 + t] * inv;
    float m = v;
    #pragma unroll
    for (int o = 32; o; o >>= 1) m = fmaxf(m, __shfl_xor(m, o));
    if ((t & 63) == 0) red[t >> 6] = m;
    __syncthreads();
    if (t < 64) {
        float mm = (t < 16) ? red[t] : -3.4e38f;
        #pragma unroll
        for (int o = 32; o; o >>= 1) mm = fmaxf(mm, __shfl_xor(mm, o));
        if (t == 0) bc[0] = mm;
    }
    __syncthreads();
    float e = expf(v - bc[0]);
    float s = e;
    #pragma unroll
    for (int o = 32; o; o >>= 1) s += __shfl_xor(s, o);
    if ((t & 63) == 0) red[t >> 6] = s;
    __syncthreads();
    if (t < 64) {
        float ss = (t < 16) ? red[t] : 0.f;
        #pragma unroll
        for (int o = 32; o; o >>= 1) ss += __shfl_xor(ss, o);
        if (t == 0) bc[1] = ss;
    }
    __syncthreads();
    cw[b * 1024 + t] = e / bc[1];
}

// ---------------- LayerNorm -> bf16 (one wave per token) ----------------
__global__ void ln_kernel(const float* __restrict__ x, const float* __restrict__ g,
                          const float* __restrict__ b, bf16_t* __restrict__ xn) {
    int token = blockIdx.x * 4 + (threadIdx.x >> 6);
    int l = threadIdx.x & 63;
    const float* xr = x + (size_t)token * 512;
    float4 v0 = ((const float4*)xr)[l * 2];
    float4 v1 = ((const float4*)xr)[l * 2 + 1];
    float s = v0.x + v0.y + v0.z + v0.w + v1.x + v1.y + v1.z + v1.w;
    float ss = v0.x * v0.x + v0.y * v0.y + v0.z * v0.z + v0.w * v0.w
             + v1.x * v1.x + v1.y * v1.y + v1.z * v1.z + v1.w * v1.w;
    #pragma unroll
    for (int o = 32; o; o >>= 1) { s += __shfl_xor(s, o); ss += __shfl_xor(ss, o); }
    float mu = s * (1.0f / 512.0f);
    float var = ss * (1.0f / 512.0f) - mu * mu;
    float rs = rsqrtf(var + 1e-5f);
    float4 g0 = ((const float4*)g)[l * 2], g1 = ((const float4*)g)[l * 2 + 1];
    float4 b0 = ((const float4*)b)[l * 2], b1 = ((const float4*)b)[l * 2 + 1];
    bf16_t* op = xn + (size_t)token * 512 + l * 8;
    op[0] = __float2bfloat16((v0.x - mu) * rs * g0.x + b0.x);
    op[1] = __float2bfloat16((v0.y - mu) * rs * g0.y + b0.y);
    op[2] = __float2bfloat16((v0.z - mu) * rs * g0.z + b0.z);
    op[3] = __float2bfloat16((v0.w - mu) * rs * g0.w + b0.w);
    op[4] = __float2bfloat16((v1.x - mu) * rs * g1.x + b1.x);
    op[5] = __float2bfloat16((v1.y - mu) * rs * g1.y + b1.y);
    op[6] = __float2bfloat16((v1.z - mu) * rs * g1.z + b1.z);
    op[7] = __float2bfloat16((v1.w - mu) * rs * g1.w + b1.w);
}

// ---------------- bf16 MFMA GEMM: C = A[M,K] @ B[N,K]^T, 128x128 tile ----------------
// MODE 0: out_bf = bf16(gelu(acc + bias[n]))        (ldc = N)
// MODE 1: x[row*ldc+n] += (acc + bias[n]) * cw[row] * 0.3
// MODE 2: out_f = acc
template <int MODE>
__global__ __launch_bounds__(256) void gemm_bt(
    const bf16_t* __restrict__ A, int lda,
    const bf16_t* __restrict__ B, int ldb, int K,
    const float* __restrict__ bias,
    bf16_t* __restrict__ out_bf, float* __restrict__ out_f, int ldc,
    const float* __restrict__ cw, float* __restrict__ x)
{
    __shared__ __align__(16) bf16_t As[128 * 32];
    __shared__ __align__(16) bf16_t Bs[128 * 32];
    const int tid = threadIdx.x;
    const int m0 = blockIdx.x * 128;
    const int n0 = blockIdx.y * 128;
    const int wave = tid >> 6, lane = tid & 63;
    const int wm = (wave >> 1) * 64, wn = (wave & 1) * 64;
    const int lr = lane & 15, kq = lane >> 4;

    f32x4_t acc[4][4] = {};

    const int srow = tid >> 2;              // 0..63
    const int scol = (tid & 3) * 8;         // bf16 elems
    const bf16_t* gA = A + (size_t)(m0 + srow) * lda + scol;
    const bf16_t* gB = B + (size_t)(n0 + srow) * ldb + scol;
    bf16_t* lA = &As[srow * 32 + scol];
    bf16_t* lB = &Bs[srow * 32 + scol];
    const size_t a64 = (size_t)64 * lda, b64 = (size_t)64 * ldb;

    for (int k0 = 0; k0 < K; k0 += 32) {
        load_lds16(gA + k0,       lA);
        load_lds16(gA + k0 + a64, lA + 64 * 32);
        load_lds16(gB + k0,       lB);
        load_lds16(gB + k0 + b64, lB + 64 * 32);
        __syncthreads();
        bf16x8_t af[4], bfr[4];
        #pragma unroll
        for (int i = 0; i < 4; ++i) {
            af[i]  = *(const bf16x8_t*)&As[(wm + i * 16 + lr) * 32 + kq * 8];
            bfr[i] = *(const bf16x8_t*)&Bs[(wn + i * 16 + lr) * 32 + kq * 8];
        }
        #pragma unroll
        for (int i = 0; i < 4; ++i)
            #pragma unroll
            for (int j = 0; j < 4; ++j)
                acc[i][j] = __builtin_amdgcn_mfma_f32_16x16x32_bf16(af[i], bfr[j], acc[i][j], 0, 0, 0);
        __syncthreads();
    }

    #pragma unroll
    for (int i = 0; i < 4; ++i) {
        const int rbase = m0 + wm + i * 16 + kq * 4;   // C/D: row=(lane>>4)*4+reg
        #pragma unroll
        for (int j = 0; j < 4; ++j) {
            const int gcol = n0 + wn + j * 16 + lr;    // C/D: col=lane&15
            #pragma unroll
            for (int r = 0; r < 4; ++r) {
                const size_t grow = (size_t)(rbase + r);
                float v = acc[i][j][r];
                if (MODE == 0) {
                    v = gelu_f(v + bias[gcol]);
                    out_bf[grow * ldc + gcol] = __float2bfloat16(v);
                } else if (MODE == 1) {
                    v += bias[gcol];
                    x[grow * ldc + gcol] += v * cw[grow] * 0.3f;
                } else {
                    out_f[grow * ldc + gcol] = v;
                }
            }
        }
    }
}

extern "C" void kernel_launch(void* const* d_in, const int* in_sizes, int n_in,
                              void* d_out, int out_size, void* d_ws, size_t ws_size,
                              hipStream_t stream) {
    const int*   tokens   = (const int*)d_in[0];
    const float* c_states = (const float*)d_in[1];
    const float* embed_w  = (const float*)d_in[2];
    const float* pos_w    = (const float*)d_in[3];
    const float* cn_w1    = (const float*)d_in[4];
    const float* cn_b1    = (const float*)d_in[5];
    const float* cn_w2    = (const float*)d_in[6];
    const float* cn_b2    = (const float*)d_in[7];
    const float* ent_w1   = (const float*)d_in[8];
    const float* ent_b1   = (const float*)d_in[9];
    const float* ent_w2   = (const float*)d_in[10];
    const float* ent_b2   = (const float*)d_in[11];
    const float* ctc_w1   = (const float*)d_in[12];
    const float* ctc_b1   = (const float*)d_in[13];
    const float* ctc_w2   = (const float*)d_in[14];
    const float* ctc_b2   = (const float*)d_in[15];
    const float* base_temp= (const float*)d_in[16];
    const float* ln_g     = (const float*)d_in[17];
    const float* ln_b     = (const float*)d_in[18];
    const float* head_w   = (const float*)d_in[19];
    float* out = (float*)d_out;

    char* ws = (char*)d_ws;
    float*  x     = (float*)(ws + OFF_X);
    bf16_t* ci    = (bf16_t*)(ws + OFF_CI);
    bf16_t* h1    = (bf16_t*)(ws + OFF_H1);
    bf16_t* xn    = (bf16_t*)(ws + OFF_XN);
    bf16_t* w1b   = (bf16_t*)(ws + OFF_W1B);
    bf16_t* w2b   = (bf16_t*)(ws + OFF_W2B);
    bf16_t* headb = (bf16_t*)(ws + OFF_CI);   // alias: ci dead after the loop
    float*  ent   = (float*)(ws + OFF_ENT);
    float*  cw    = (float*)(ws + OFF_CW);
    float*  hc    = (float*)(ws + OFF_HC);
    float*  cc    = (float*)(ws + OFF_CC);
    float*  bias1 = (float*)(ws + OFF_B1);

    // weight converts + constant path
    cvt_w1_kernel<<<1536, 256, 0, stream>>>(cn_w1, w1b);               // 1024*384 quads
    cvt_kernel<<<512, 256, 0, stream>>>(cn_w2, w2b);                   // 512*1024/4
    prep1_kernel<<<4, 256, 0, stream>>>(c_states, ctc_w1, ctc_b1, hc);
    prep2_kernel<<<2, 256, 0, stream>>>(hc, ctc_w2, ctc_b2, cc);
    prep3_kernel<<<4, 256, 0, stream>>>(cc, cn_w1, cn_b1, bias1);
    embed_kernel<<<4096, 256, 0, stream>>>(tokens, embed_w, pos_w, x); // 8192*128 quads

    for (int step = 0; step < 6; ++step) {
        float stepf = 1.0f - ((float)step / 6.0f) * 0.8f;
        entropy_kernel<<<2048, 256, 0, stream>>>(x, ent_w1, ent_b1, ent_w2, ent_b2, ent);
        softmax_kernel<<<8, 1024, 0, stream>>>(ent, base_temp, stepf, cw);
        ci_kernel<<<12288, 256, 0, stream>>>(x, ci);                   // 8192*384 quads
        gemm_bt<0><<<dim3(64, 8), 256, 0, stream>>>(ci, 1536, w1b, 1536, 1536,
                                                    bias1, h1, nullptr, 1024, nullptr, nullptr);
        gemm_bt<1><<<dim3(64, 4), 256, 0, stream>>>(h1, 1024, w2b, 1024, 1024,
                                                    cn_b2, nullptr, nullptr, 512, cw, x);
    }

    cvt_kernel<<<16000, 256, 0, stream>>>(head_w, headb);              // 32000*512/4
    ln_kernel<<<2048, 256, 0, stream>>>(x, ln_g, ln_b, xn);
    gemm_bt<2><<<dim3(64, 250), 256, 0, stream>>>(xn, 512, headb, 512, 512,
                                                  nullptr, nullptr, out, 32000, nullptr, nullptr);
}

// Round 2
// 1346.167 us; speedup vs baseline: 1.5038x; 1.5038x over previous
//
#include <hip/hip_runtime.h>
#include <hip/hip_bf16.h>

typedef __hip_bfloat16 bf16_t;
typedef __bf16 bf16x8_t __attribute__((ext_vector_type(8)));
typedef float f32x4_t __attribute__((ext_vector_type(4)));

// ---------------- workspace layout (bytes) ----------------
#define OFF_X     ((size_t)0)          // 8192*512  f32  = 16,777,216
#define OFF_XB    ((size_t)16777216)   // 8192*512  bf16 =  8,388,608
#define OFF_H1    ((size_t)25165824)   // 8192*1024 bf16 = 16,777,216
#define OFF_XN    ((size_t)41943040)   // 8192*512  bf16 =  8,388,608
#define OFF_HEADB ((size_t)50331648)   // 32000*512 bf16 = 32,768,000
#define OFF_W1B   ((size_t)83099648)   // 1024*1536 bf16 =  3,145,728
#define OFF_W2B   ((size_t)86245376)   // 512*1024  bf16 =  1,048,576
#define OFF_EW1   ((size_t)87293952)   // 64*512    bf16 =     65,536
#define OFF_ENT   ((size_t)87359488)   // 8192 f32
#define OFF_CW    ((size_t)87392256)   // 8192 f32
#define OFF_HC    ((size_t)87425024)   // 1024 f32
#define OFF_CC    ((size_t)87429120)   // 512  f32
#define OFF_B1    ((size_t)87431168)   // 1024 f32

__device__ __forceinline__ float gelu_f(float v) {
    return 0.5f * v * (1.0f + erff(v * 0.7071067811865475f));
}

__device__ __forceinline__ void load_lds16(const bf16_t* g, bf16_t* l) {
    __builtin_amdgcn_global_load_lds(
        (const __attribute__((address_space(1))) void*)g,
        (__attribute__((address_space(3))) void*)l, 16, 0, 0);
}

// ---------------- prep: ctc MLP on pooled c_states, fold into bias1 ----------------
__global__ void prep1_kernel(const float* __restrict__ cs, const float* __restrict__ w1,
                             const float* __restrict__ b1, float* __restrict__ hc) {
    int o = blockIdx.x * 256 + threadIdx.x;            // 0..1023
    const float* wr = w1 + (size_t)o * 512;
    float acc = 0.f;
    for (int k = 0; k < 512; k += 4) {
        float4 w4 = *(const float4*)(wr + k);
        float4 a = *(const float4*)(cs + k);
        float4 b = *(const float4*)(cs + 512 + k);
        float4 c = *(const float4*)(cs + 1024 + k);
        float4 d = *(const float4*)(cs + 1536 + k);
        acc += w4.x * (a.x + b.x + c.x + d.x) * 0.25f;
        acc += w4.y * (a.y + b.y + c.y + d.y) * 0.25f;
        acc += w4.z * (a.z + b.z + c.z + d.z) * 0.25f;
        acc += w4.w * (a.w + b.w + c.w + d.w) * 0.25f;
    }
    hc[o] = gelu_f(acc + b1[o]);
}

__global__ void prep2_kernel(const float* __restrict__ hc, const float* __restrict__ w2,
                             const float* __restrict__ b2, float* __restrict__ cc) {
    int o = blockIdx.x * 256 + threadIdx.x;            // 0..511
    const float* wr = w2 + (size_t)o * 1024;
    float acc = 0.f;
    for (int k = 0; k < 1024; ++k) acc += wr[k] * hc[k];
    cc[o] = acc + b2[o];
}

__global__ void prep3_kernel(const float* __restrict__ cc, const float* __restrict__ cn_w1,
                             const float* __restrict__ cn_b1, float* __restrict__ bias1) {
    int o = blockIdx.x * 256 + threadIdx.x;            // 0..1023
    const float* wr = cn_w1 + (size_t)o * 2048 + 1536;
    float acc = 0.f;
    for (int k = 0; k < 512; ++k) acc += wr[k] * cc[k];
    bias1[o] = acc + cn_b1[o];
}

// ---------------- embed + pos -> x (f32) and xb (bf16) ----------------
__global__ void embed_kernel(const int* __restrict__ tokens, const float* __restrict__ ew,
                             const float* __restrict__ pw, float* __restrict__ x,
                             bf16_t* __restrict__ xb) {
    int idx = blockIdx.x * 256 + threadIdx.x;          // quad id, total 8192*128
    int d4 = idx & 127;
    int bt = idx >> 7;
    int t = bt & 1023;
    int tok = tokens[bt];
    float4 e = ((const float4*)(ew + (size_t)tok * 512))[d4];
    float4 p = ((const float4*)(pw + (size_t)t * 512))[d4];
    float4 o = make_float4(e.x + p.x, e.y + p.y, e.z + p.z, e.w + p.w);
    ((float4*)x)[idx] = o;
    __hip_bfloat162 p0, p1;
    p0.x = __float2bfloat16(o.x); p0.y = __float2bfloat16(o.y);
    p1.x = __float2bfloat16(o.z); p1.y = __float2bfloat16(o.w);
    ((__hip_bfloat162*)xb)[idx * 2]     = p0;
    ((__hip_bfloat162*)xb)[idx * 2 + 1] = p1;
}

// ---------------- f32 -> bf16 converts ----------------
__global__ void cvt_kernel(const float* __restrict__ src, bf16_t* __restrict__ dst) {
    int idx = blockIdx.x * 256 + threadIdx.x;          // quad id, grid sized exactly
    float4 v = ((const float4*)src)[idx];
    __hip_bfloat162 p0, p1;
    p0.x = __float2bfloat16(v.x); p0.y = __float2bfloat16(v.y);
    p1.x = __float2bfloat16(v.z); p1.y = __float2bfloat16(v.w);
    ((__hip_bfloat162*)dst)[idx * 2]     = p0;
    ((__hip_bfloat162*)dst)[idx * 2 + 1] = p1;
}

__global__ void cvt_w1_kernel(const float* __restrict__ w1, bf16_t* __restrict__ dst) {
    int idx = blockIdx.x * 256 + threadIdx.x;          // quad id, total 1024*384
    int k4 = idx % 384;
    int o = idx / 384;
    float4 v = ((const float4*)(w1 + (size_t)o * 2048))[k4];
    __hip_bfloat162 p0, p1;
    p0.x = __float2bfloat16(v.x); p0.y = __float2bfloat16(v.y);
    p1.x = __float2bfloat16(v.z); p1.y = __float2bfloat16(v.w);
    ((__hip_bfloat162*)dst)[idx * 2]     = p0;
    ((__hip_bfloat162*)dst)[idx * 2 + 1] = p1;
}

// ---------------- entropy MLP via MFMA: 16 tokens per wave ----------------
__global__ __launch_bounds__(256) void entropy_mfma(
        const bf16_t* __restrict__ xb, const bf16_t* __restrict__ w1b,
        const float* __restrict__ b1, const float* __restrict__ w2,
        const float* __restrict__ b2, float* __restrict__ ent) {
    int wave = threadIdx.x >> 6, lane = threadIdx.x & 63;
    int lr = lane & 15, kq = lane >> 4;
    int tok0 = (blockIdx.x * 4 + wave) * 16;
    f32x4_t acc[4] = {};
    const bf16_t* xr = xb + (size_t)(tok0 + lr) * 512 + kq * 8;
    const bf16_t* wr = w1b + (size_t)lr * 512 + kq * 8;
    #pragma unroll 4
    for (int k0 = 0; k0 < 512; k0 += 32) {
        bf16x8_t a = *(const bf16x8_t*)(xr + k0);
        #pragma unroll
        for (int j = 0; j < 4; ++j) {
            bf16x8_t bb = *(const bf16x8_t*)(wr + (size_t)j * 16 * 512 + k0);
            acc[j] = __builtin_amdgcn_mfma_f32_16x16x32_bf16(a, bb, acc[j], 0, 0, 0);
        }
    }
    // lane holds tokens kq*4+r (r=0..3), hidden n=j*16+lr
    float p[4];
    #pragma unroll
    for (int r = 0; r < 4; ++r) {
        float s = 0.f;
        #pragma unroll
        for (int j = 0; j < 4; ++j) {
            int n = j * 16 + lr;
            s += gelu_f(acc[j][r] + b1[n]) * w2[n];
        }
        #pragma unroll
        for (int o = 1; o < 16; o <<= 1) s += __shfl_xor(s, o);
        p[r] = s;
    }
    if (lr == 0) {
        float bb = b2[0];
        #pragma unroll
        for (int r = 0; r < 4; ++r) ent[tok0 + kq * 4 + r] = p[r] + bb;
    }
}

// ---------------- softmax over T (per batch) ----------------
__global__ void softmax_kernel(const float* __restrict__ ent, const float* __restrict__ btp,
                               float stepf, float* __restrict__ cw) {
    __shared__ float red[16];
    __shared__ float bc[2];
    int b = blockIdx.x, t = threadIdx.x;               // 1024 threads
    float bt = btp[0];
    float sp = (bt > 20.0f) ? bt : log1pf(expf(bt));
    float inv = -1.0f / (sp * stepf);
    float v = ent[b * 1024 + t] * inv;
    float m = v;
    #pragma unroll
    for (int o = 32; o; o >>= 1) m = fmaxf(m, __shfl_xor(m, o));
    if ((t & 63) == 0) red[t >> 6] = m;
    __syncthreads();
    if (t < 64) {
        float mm = (t < 16) ? red[t] : -3.4e38f;
        #pragma unroll
        for (int o = 32; o; o >>= 1) mm = fmaxf(mm, __shfl_xor(mm, o));
        if (t == 0) bc[0] = mm;
    }
    __syncthreads();
    float e = expf(v - bc[0]);
    float s = e;
    #pragma unroll
    for (int o = 32; o; o >>= 1) s += __shfl_xor(s, o);
    if ((t & 63) == 0) red[t >> 6] = s;
    __syncthreads();
    if (t < 64) {
        float ss = (t < 16) ? red[t] : 0.f;
        #pragma unroll
        for (int o = 32; o; o >>= 1) ss += __shfl_xor(ss, o);
        if (t == 0) bc[1] = ss;
    }
    __syncthreads();
    cw[b * 1024 + t] = e / bc[1];
}

// ---------------- LayerNorm -> bf16 (one wave per token) ----------------
__global__ void ln_kernel(const float* __restrict__ x, const float* __restrict__ g,
                          const float* __restrict__ b, bf16_t* __restrict__ xn) {
    int token = blockIdx.x * 4 + (threadIdx.x >> 6);
    int l = threadIdx.x & 63;
    const float* xr = x + (size_t)token * 512;
    float4 v0 = ((const float4*)xr)[l * 2];
    float4 v1 = ((const float4*)xr)[l * 2 + 1];
    float s = v0.x + v0.y + v0.z + v0.w + v1.x + v1.y + v1.z + v1.w;
    float ss = v0.x * v0.x + v0.y * v0.y + v0.z * v0.z + v0.w * v0.w
             + v1.x * v1.x + v1.y * v1.y + v1.z * v1.z + v1.w * v1.w;
    #pragma unroll
    for (int o = 32; o; o >>= 1) { s += __shfl_xor(s, o); ss += __shfl_xor(ss, o); }
    float mu = s * (1.0f / 512.0f);
    float var = ss * (1.0f / 512.0f) - mu * mu;
    float rs = rsqrtf(var + 1e-5f);
    float4 g0 = ((const float4*)g)[l * 2], g1 = ((const float4*)g)[l * 2 + 1];
    float4 b0 = ((const float4*)b)[l * 2], b1 = ((const float4*)b)[l * 2 + 1];
    bf16_t* op = xn + (size_t)token * 512 + l * 8;
    op[0] = __float2bfloat16((v0.x - mu) * rs * g0.x + b0.x);
    op[1] = __float2bfloat16((v0.y - mu) * rs * g0.y + b0.y);
    op[2] = __float2bfloat16((v0.z - mu) * rs * g0.z + b0.z);
    op[3] = __float2bfloat16((v0.w - mu) * rs * g0.w + b0.w);
    op[4] = __float2bfloat16((v1.x - mu) * rs * g1.x + b1.x);
    op[5] = __float2bfloat16((v1.y - mu) * rs * g1.y + b1.y);
    op[6] = __float2bfloat16((v1.z - mu) * rs * g1.z + b1.z);
    op[7] = __float2bfloat16((v1.w - mu) * rs * g1.w + b1.w);
}

// ---------------- 128x128 bf16 MFMA GEMM: C = A[M,K] @ B[N,K]^T ----------------
// MODE 0: out_bf = bf16(gelu(acc + bias[n]))        (ldc = N)
//   ROLL: A is xb [8192x512]; K=1536 spans segs {t, t-1, t+1} of 512 each
// MODE 1: nv = x[row*ldc+n] + (acc + bias[n]) * cw[row] * 0.3; x=nv; out_bf(xb)=bf16(nv)
template <int MODE, int ROLL>
__global__ __launch_bounds__(256) void gemm_bt(
    const bf16_t* __restrict__ A, int lda,
    const bf16_t* __restrict__ B, int ldb, int K,
    const float* __restrict__ bias,
    bf16_t* __restrict__ out_bf, int ldc,
    const float* __restrict__ cw, float* __restrict__ x)
{
    __shared__ __align__(16) bf16_t As[128 * 32];
    __shared__ __align__(16) bf16_t Bs[128 * 32];
    const int tid = threadIdx.x;
    const int m0 = blockIdx.x * 128;
    const int n0 = blockIdx.y * 128;
    const int wave = tid >> 6, lane = tid & 63;
    const int wm = (wave >> 1) * 64, wn = (wave & 1) * 64;
    const int lr = lane & 15, kq = lane >> 4;

    f32x4_t acc[4][4] = {};

    const int srow = tid >> 2;              // 0..63
    const int scol = (tid & 3) * 8;         // bf16 elems
    const bf16_t* gA = A + (size_t)(m0 + srow) * lda + scol;
    const bf16_t* gB = B + (size_t)(n0 + srow) * ldb + scol;
    bf16_t* lA = &As[srow * 32 + scol];
    bf16_t* lB = &Bs[srow * 32 + scol];
    const size_t a64 = (size_t)64 * lda, b64 = (size_t)64 * ldb;

    for (int k0 = 0; k0 < K; k0 += 32) {
        if (ROLL) {
            const int seg = k0 >> 9;
            const int kk = k0 & 511;
            const int sh = (seg == 0) ? 0 : ((seg == 1) ? 1023 : 1);
            const int r1 = m0 + srow;
            const int r2 = r1 + 64;
            const bf16_t* g1 = A + (size_t)((r1 & ~1023) | (((r1 & 1023) + sh) & 1023)) * 512 + kk + scol;
            const bf16_t* g2 = A + (size_t)((r2 & ~1023) | (((r2 & 1023) + sh) & 1023)) * 512 + kk + scol;
            load_lds16(g1, lA);
            load_lds16(g2, lA + 64 * 32);
        } else {
            load_lds16(gA + k0,       lA);
            load_lds16(gA + k0 + a64, lA + 64 * 32);
        }
        load_lds16(gB + k0,       lB);
        load_lds16(gB + k0 + b64, lB + 64 * 32);
        __syncthreads();
        bf16x8_t af[4], bfr[4];
        #pragma unroll
        for (int i = 0; i < 4; ++i) {
            af[i]  = *(const bf16x8_t*)&As[(wm + i * 16 + lr) * 32 + kq * 8];
            bfr[i] = *(const bf16x8_t*)&Bs[(wn + i * 16 + lr) * 32 + kq * 8];
        }
        #pragma unroll
        for (int i = 0; i < 4; ++i)
            #pragma unroll
            for (int j = 0; j < 4; ++j)
                acc[i][j] = __builtin_amdgcn_mfma_f32_16x16x32_bf16(af[i], bfr[j], acc[i][j], 0, 0, 0);
        __syncthreads();
    }

    #pragma unroll
    for (int i = 0; i < 4; ++i) {
        const int rbase = m0 + wm + i * 16 + kq * 4;   // C/D: row=(lane>>4)*4+reg
        #pragma unroll
        for (int j = 0; j < 4; ++j) {
            const int gcol = n0 + wn + j * 16 + lr;    // C/D: col=lane&15
            #pragma unroll
            for (int r = 0; r < 4; ++r) {
                const size_t grow = (size_t)(rbase + r);
                float v = acc[i][j][r];
                if (MODE == 0) {
                    v = gelu_f(v + bias[gcol]);
                    out_bf[grow * ldc + gcol] = __float2bfloat16(v);
                } else {
                    v += bias[gcol];
                    float nv = x[grow * ldc + gcol] + v * cw[grow] * 0.3f;
                    x[grow * ldc + gcol] = nv;
                    out_bf[grow * ldc + gcol] = __float2bfloat16(nv);
                }
            }
        }
    }
}

// ---------------- head GEMM: 256x256 tile, 512 threads, out = xn @ headb^T ----------------
__global__ __launch_bounds__(512) void gemm_head(
    const bf16_t* __restrict__ A,     // [8192 x 512]
    const bf16_t* __restrict__ B,     // [32000 x 512]
    float* __restrict__ out)          // [8192 x 32000]
{
    __shared__ __align__(16) bf16_t As[256 * 32];
    __shared__ __align__(16) bf16_t Bs[256 * 32];
    // bijective XCD-chunked swizzle: nwg = 32*125 = 4000, 4000 % 8 == 0
    const int id = blockIdx.x + blockIdx.y * 32;
    const int nid = (id & 7) * 500 + (id >> 3);
    const int m0 = (nid & 31) * 256;
    const int n0 = (nid >> 5) * 256;

    const int tid = threadIdx.x;
    const int wave = tid >> 6, lane = tid & 63;
    const int wm = (wave >> 2) * 128, wn = (wave & 3) * 64;
    const int lr = lane & 15, kq = lane >> 4;

    f32x4_t acc[8][4] = {};

    const int srow = tid >> 2;              // 0..127
    const int scol = (tid & 3) * 8;
    const bf16_t* gA = A + (size_t)(m0 + srow) * 512 + scol;
    const bf16_t* gB = B + (size_t)(n0 + srow) * 512 + scol;
    bf16_t* lA = &As[srow * 32 + scol];
    bf16_t* lB = &Bs[srow * 32 + scol];
    const size_t s128 = (size_t)128 * 512;

    for (int k0 = 0; k0 < 512; k0 += 32) {
        load_lds16(gA + k0,        lA);
        load_lds16(gA + k0 + s128, lA + 128 * 32);
        load_lds16(gB + k0,        lB);
        load_lds16(gB + k0 + s128, lB + 128 * 32);
        __syncthreads();
        bf16x8_t af[8], bfr[4];
        #pragma unroll
        for (int i = 0; i < 8; ++i)
            af[i]  = *(const bf16x8_t*)&As[(wm + i * 16 + lr) * 32 + kq * 8];
        #pragma unroll
        for (int j = 0; j < 4; ++j)
            bfr[j] = *(const bf16x8_t*)&Bs[(wn + j * 16 + lr) * 32 + kq * 8];
        #pragma unroll
        for (int i = 0; i < 8; ++i)
            #pragma unroll
            for (int j = 0; j < 4; ++j)
                acc[i][j] = __builtin_amdgcn_mfma_f32_16x16x32_bf16(af[i], bfr[j], acc[i][j], 0, 0, 0);
        __syncthreads();
    }

    #pragma unroll
    for (int i = 0; i < 8; ++i) {
        const int rbase = m0 + wm + i * 16 + kq * 4;
        #pragma unroll
        for (int j = 0; j < 4; ++j) {
            const int gcol = n0 + wn + j * 16 + lr;
            #pragma unroll
            for (int r = 0; r < 4; ++r)
                out[(size_t)(rbase + r) * 32000 + gcol] = acc[i][j][r];
        }
    }
}

extern "C" void kernel_launch(void* const* d_in, const int* in_sizes, int n_in,
                              void* d_out, int out_size, void* d_ws, size_t ws_size,
                              hipStream_t stream) {
    const int*   tokens   = (const int*)d_in[0];
    const float* c_states = (const float*)d_in[1];
    const float* embed_w  = (const float*)d_in[2];
    const float* pos_w    = (const float*)d_in[3];
    const float* cn_w1    = (const float*)d_in[4];
    const float* cn_b1    = (const float*)d_in[5];
    const float* cn_b2    = (const float*)d_in[7];
    const float* cn_w2    = (const float*)d_in[6];
    const float* ent_w1   = (const float*)d_in[8];
    const float* ent_b1   = (const float*)d_in[9];
    const float* ent_w2   = (const float*)d_in[10];
    const float* ent_b2   = (const float*)d_in[11];
    const float* ctc_w1   = (const float*)d_in[12];
    const float* ctc_b1   = (const float*)d_in[13];
    const float* ctc_w2   = (const float*)d_in[14];
    const float* ctc_b2   = (const float*)d_in[15];
    const float* base_temp= (const float*)d_in[16];
    const float* ln_g     = (const float*)d_in[17];
    const float* ln_b     = (const float*)d_in[18];
    const float* head_w   = (const float*)d_in[19];
    float* out = (float*)d_out;

    char* ws = (char*)d_ws;
    float*  x     = (float*)(ws + OFF_X);
    bf16_t* xb    = (bf16_t*)(ws + OFF_XB);
    bf16_t* h1    = (bf16_t*)(ws + OFF_H1);
    bf16_t* xn    = (bf16_t*)(ws + OFF_XN);
    bf16_t* headb = (bf16_t*)(ws + OFF_HEADB);
    bf16_t* w1b   = (bf16_t*)(ws + OFF_W1B);
    bf16_t* w2b   = (bf16_t*)(ws + OFF_W2B);
    bf16_t* ew1b  = (bf16_t*)(ws + OFF_EW1);
    float*  ent   = (float*)(ws + OFF_ENT);
    float*  cw    = (float*)(ws + OFF_CW);
    float*  hc    = (float*)(ws + OFF_HC);
    float*  cc    = (float*)(ws + OFF_CC);
    float*  bias1 = (float*)(ws + OFF_B1);

    // weight converts + constant path
    cvt_w1_kernel<<<1536, 256, 0, stream>>>(cn_w1, w1b);               // 1024*384 quads
    cvt_kernel<<<512, 256, 0, stream>>>(cn_w2, w2b);                   // 512*1024/4
    cvt_kernel<<<32, 256, 0, stream>>>(ent_w1, ew1b);                  // 64*512/4
    prep1_kernel<<<4, 256, 0, stream>>>(c_states, ctc_w1, ctc_b1, hc);
    prep2_kernel<<<2, 256, 0, stream>>>(hc, ctc_w2, ctc_b2, cc);
    prep3_kernel<<<4, 256, 0, stream>>>(cc, cn_w1, cn_b1, bias1);
    embed_kernel<<<4096, 256, 0, stream>>>(tokens, embed_w, pos_w, x, xb);

    for (int step = 0; step < 6; ++step) {
        float stepf = 1.0f - ((float)step / 6.0f) * 0.8f;
        entropy_mfma<<<128, 256, 0, stream>>>(xb, ew1b, ent_b1, ent_w2, ent_b2, ent);
        softmax_kernel<<<8, 1024, 0, stream>>>(ent, base_temp, stepf, cw);
        gemm_bt<0, 1><<<dim3(64, 8), 256, 0, stream>>>(xb, 512, w1b, 1536, 1536,
                                                       bias1, h1, 1024, nullptr, nullptr);
        gemm_bt<1, 0><<<dim3(64, 4), 256, 0, stream>>>(h1, 1024, w2b, 1024, 1024,
                                                       cn_b2, xb, 512, cw, x);
    }

    cvt_kernel<<<16000, 256, 0, stream>>>(head_w, headb);              // 32000*512/4
    ln_kernel<<<2048, 256, 0, stream>>>(x, ln_g, ln_b, xn);
    gemm_head<<<dim3(32, 125), 512, 0, stream>>>(xn, headb, out);
}

// Round 3
// 1298.780 us; speedup vs baseline: 1.5586x; 1.0365x over previous
//
#include <hip/hip_runtime.h>
#include <hip/hip_bf16.h>

typedef __hip_bfloat16 bf16_t;
typedef __bf16 bf16x8_t __attribute__((ext_vector_type(8)));
typedef float f32x4_t __attribute__((ext_vector_type(4)));

// ---------------- workspace layout (bytes) ----------------
#define OFF_X     ((size_t)0)          // 8192*512  f32  = 16,777,216
#define OFF_XB    ((size_t)16777216)   // 8192*512  bf16 =  8,388,608
#define OFF_H1    ((size_t)25165824)   // 8192*1024 bf16 = 16,777,216
#define OFF_XN    ((size_t)41943040)   // 8192*512  bf16 =  8,388,608
#define OFF_HEADB ((size_t)50331648)   // 32000*512 bf16 = 32,768,000
#define OFF_W1B   ((size_t)83099648)   // 1024*1536 bf16 =  3,145,728
#define OFF_W2B   ((size_t)86245376)   // 512*1024  bf16 =  1,048,576
#define OFF_EW1   ((size_t)87293952)   // 64*512    bf16 =     65,536
#define OFF_ENT   ((size_t)87359488)   // 8192 f32
#define OFF_CW    ((size_t)87392256)   // 8192 f32
#define OFF_HC    ((size_t)87425024)   // 1024 f32
#define OFF_CC    ((size_t)87429120)   // 512  f32
#define OFF_B1    ((size_t)87431168)   // 1024 f32

__device__ __forceinline__ float gelu_f(float v) {
    return 0.5f * v * (1.0f + erff(v * 0.7071067811865475f));
}

__device__ __forceinline__ void load_lds16(const bf16_t* g, bf16_t* l) {
    __builtin_amdgcn_global_load_lds(
        (const __attribute__((address_space(1))) void*)g,
        (__attribute__((address_space(3))) void*)l, 16, 0, 0);
}

// ---------------- prep: ctc MLP on pooled c_states, fold into bias1 ----------------
__global__ void prep1_kernel(const float* __restrict__ cs, const float* __restrict__ w1,
                             const float* __restrict__ b1, float* __restrict__ hc) {
    int o = blockIdx.x * 256 + threadIdx.x;            // 0..1023
    const float* wr = w1 + (size_t)o * 512;
    float acc = 0.f;
    for (int k = 0; k < 512; k += 4) {
        float4 w4 = *(const float4*)(wr + k);
        float4 a = *(const float4*)(cs + k);
        float4 b = *(const float4*)(cs + 512 + k);
        float4 c = *(const float4*)(cs + 1024 + k);
        float4 d = *(const float4*)(cs + 1536 + k);
        acc += w4.x * (a.x + b.x + c.x + d.x) * 0.25f;
        acc += w4.y * (a.y + b.y + c.y + d.y) * 0.25f;
        acc += w4.z * (a.z + b.z + c.z + d.z) * 0.25f;
        acc += w4.w * (a.w + b.w + c.w + d.w) * 0.25f;
    }
    hc[o] = gelu_f(acc + b1[o]);
}

__global__ void prep2_kernel(const float* __restrict__ hc, const float* __restrict__ w2,
                             const float* __restrict__ b2, float* __restrict__ cc) {
    int o = blockIdx.x * 256 + threadIdx.x;            // 0..511
    const float* wr = w2 + (size_t)o * 1024;
    float acc = 0.f;
    for (int k = 0; k < 1024; ++k) acc += wr[k] * hc[k];
    cc[o] = acc + b2[o];
}

__global__ void prep3_kernel(const float* __restrict__ cc, const float* __restrict__ cn_w1,
                             const float* __restrict__ cn_b1, float* __restrict__ bias1) {
    int o = blockIdx.x * 256 + threadIdx.x;            // 0..1023
    const float* wr = cn_w1 + (size_t)o * 2048 + 1536;
    float acc = 0.f;
    for (int k = 0; k < 512; ++k) acc += wr[k] * cc[k];
    bias1[o] = acc + cn_b1[o];
}

// ---------------- embed + pos -> x (f32) and xb (bf16) ----------------
__global__ void embed_kernel(const int* __restrict__ tokens, const float* __restrict__ ew,
                             const float* __restrict__ pw, float* __restrict__ x,
                             bf16_t* __restrict__ xb) {
    int idx = blockIdx.x * 256 + threadIdx.x;          // quad id, total 8192*128
    int d4 = idx & 127;
    int bt = idx >> 7;
    int t = bt & 1023;
    int tok = tokens[bt];
    float4 e = ((const float4*)(ew + (size_t)tok * 512))[d4];
    float4 p = ((const float4*)(pw + (size_t)t * 512))[d4];
    float4 o = make_float4(e.x + p.x, e.y + p.y, e.z + p.z, e.w + p.w);
    ((float4*)x)[idx] = o;
    __hip_bfloat162 p0, p1;
    p0.x = __float2bfloat16(o.x); p0.y = __float2bfloat16(o.y);
    p1.x = __float2bfloat16(o.z); p1.y = __float2bfloat16(o.w);
    ((__hip_bfloat162*)xb)[idx * 2]     = p0;
    ((__hip_bfloat162*)xb)[idx * 2 + 1] = p1;
}

// ---------------- f32 -> bf16 converts ----------------
__global__ void cvt_kernel(const float* __restrict__ src, bf16_t* __restrict__ dst) {
    int idx = blockIdx.x * 256 + threadIdx.x;          // quad id, grid sized exactly
    float4 v = ((const float4*)src)[idx];
    __hip_bfloat162 p0, p1;
    p0.x = __float2bfloat16(v.x); p0.y = __float2bfloat16(v.y);
    p1.x = __float2bfloat16(v.z); p1.y = __float2bfloat16(v.w);
    ((__hip_bfloat162*)dst)[idx * 2]     = p0;
    ((__hip_bfloat162*)dst)[idx * 2 + 1] = p1;
}

__global__ void cvt_w1_kernel(const float* __restrict__ w1, bf16_t* __restrict__ dst) {
    int idx = blockIdx.x * 256 + threadIdx.x;          // quad id, total 1024*384
    int k4 = idx % 384;
    int o = idx / 384;
    float4 v = ((const float4*)(w1 + (size_t)o * 2048))[k4];
    __hip_bfloat162 p0, p1;
    p0.x = __float2bfloat16(v.x); p0.y = __float2bfloat16(v.y);
    p1.x = __float2bfloat16(v.z); p1.y = __float2bfloat16(v.w);
    ((__hip_bfloat162*)dst)[idx * 2]     = p0;
    ((__hip_bfloat162*)dst)[idx * 2 + 1] = p1;
}

// ---------------- entropy MLP via MFMA: 16 tokens per wave ----------------
__global__ __launch_bounds__(256) void entropy_mfma(
        const bf16_t* __restrict__ xb, const bf16_t* __restrict__ w1b,
        const float* __restrict__ b1, const float* __restrict__ w2,
        const float* __restrict__ b2, float* __restrict__ ent) {
    int wave = threadIdx.x >> 6, lane = threadIdx.x & 63;
    int lr = lane & 15, kq = lane >> 4;
    int tok0 = (blockIdx.x * 4 + wave) * 16;
    f32x4_t acc[4] = {};
    const bf16_t* xr = xb + (size_t)(tok0 + lr) * 512 + kq * 8;
    const bf16_t* wr = w1b + (size_t)lr * 512 + kq * 8;
    #pragma unroll 4
    for (int k0 = 0; k0 < 512; k0 += 32) {
        bf16x8_t a = *(const bf16x8_t*)(xr + k0);
        #pragma unroll
        for (int j = 0; j < 4; ++j) {
            bf16x8_t bb = *(const bf16x8_t*)(wr + (size_t)j * 16 * 512 + k0);
            acc[j] = __builtin_amdgcn_mfma_f32_16x16x32_bf16(a, bb, acc[j], 0, 0, 0);
        }
    }
    // lane holds tokens kq*4+r (r=0..3), hidden n=j*16+lr
    float p[4];
    #pragma unroll
    for (int r = 0; r < 4; ++r) {
        float s = 0.f;
        #pragma unroll
        for (int j = 0; j < 4; ++j) {
            int n = j * 16 + lr;
            s += gelu_f(acc[j][r] + b1[n]) * w2[n];
        }
        #pragma unroll
        for (int o = 1; o < 16; o <<= 1) s += __shfl_xor(s, o);
        p[r] = s;
    }
    if (lr == 0) {
        float bb = b2[0];
        #pragma unroll
        for (int r = 0; r < 4; ++r) ent[tok0 + kq * 4 + r] = p[r] + bb;
    }
}

// ---------------- softmax over T (per batch) ----------------
__global__ void softmax_kernel(const float* __restrict__ ent, const float* __restrict__ btp,
                               float stepf, float* __restrict__ cw) {
    __shared__ float red[16];
    __shared__ float bc[2];
    int b = blockIdx.x, t = threadIdx.x;               // 1024 threads
    float bt = btp[0];
    float sp = (bt > 20.0f) ? bt : log1pf(expf(bt));
    float inv = -1.0f / (sp * stepf);
    float v = ent[b * 1024 + t] * inv;
    float m = v;
    #pragma unroll
    for (int o = 32; o; o >>= 1) m = fmaxf(m, __shfl_xor(m, o));
    if ((t & 63) == 0) red[t >> 6] = m;
    __syncthreads();
    if (t < 64) {
        float mm = (t < 16) ? red[t] : -3.4e38f;
        #pragma unroll
        for (int o = 32; o; o >>= 1) mm = fmaxf(mm, __shfl_xor(mm, o));
        if (t == 0) bc[0] = mm;
    }
    __syncthreads();
    float e = expf(v - bc[0]);
    float s = e;
    #pragma unroll
    for (int o = 32; o; o >>= 1) s += __shfl_xor(s, o);
    if ((t & 63) == 0) red[t >> 6] = s;
    __syncthreads();
    if (t < 64) {
        float ss = (t < 16) ? red[t] : 0.f;
        #pragma unroll
        for (int o = 32; o; o >>= 1) ss += __shfl_xor(ss, o);
        if (t == 0) bc[1] = ss;
    }
    __syncthreads();
    cw[b * 1024 + t] = e / bc[1];
}

// ---------------- LayerNorm -> bf16 (one wave per token) ----------------
__global__ void ln_kernel(const float* __restrict__ x, const float* __restrict__ g,
                          const float* __restrict__ b, bf16_t* __restrict__ xn) {
    int token = blockIdx.x * 4 + (threadIdx.x >> 6);
    int l = threadIdx.x & 63;
    const float* xr = x + (size_t)token * 512;
    float4 v0 = ((const float4*)xr)[l * 2];
    float4 v1 = ((const float4*)xr)[l * 2 + 1];
    float s = v0.x + v0.y + v0.z + v0.w + v1.x + v1.y + v1.z + v1.w;
    float ss = v0.x * v0.x + v0.y * v0.y + v0.z * v0.z + v0.w * v0.w
             + v1.x * v1.x + v1.y * v1.y + v1.z * v1.z + v1.w * v1.w;
    #pragma unroll
    for (int o = 32; o; o >>= 1) { s += __shfl_xor(s, o); ss += __shfl_xor(ss, o); }
    float mu = s * (1.0f / 512.0f);
    float var = ss * (1.0f / 512.0f) - mu * mu;
    float rs = rsqrtf(var + 1e-5f);
    float4 g0 = ((const float4*)g)[l * 2], g1 = ((const float4*)g)[l * 2 + 1];
    float4 b0 = ((const float4*)b)[l * 2], b1 = ((const float4*)b)[l * 2 + 1];
    bf16_t* op = xn + (size_t)token * 512 + l * 8;
    op[0] = __float2bfloat16((v0.x - mu) * rs * g0.x + b0.x);
    op[1] = __float2bfloat16((v0.y - mu) * rs * g0.y + b0.y);
    op[2] = __float2bfloat16((v0.z - mu) * rs * g0.z + b0.z);
    op[3] = __float2bfloat16((v0.w - mu) * rs * g0.w + b0.w);
    op[4] = __float2bfloat16((v1.x - mu) * rs * g1.x + b1.x);
    op[5] = __float2bfloat16((v1.y - mu) * rs * g1.y + b1.y);
    op[6] = __float2bfloat16((v1.z - mu) * rs * g1.z + b1.z);
    op[7] = __float2bfloat16((v1.w - mu) * rs * g1.w + b1.w);
}

// ---------------- 128x128 bf16 MFMA GEMM, double-buffered 2-phase ----------------
// C = A[M,K] @ B[N,K]^T
// MODE 0: out_bf = bf16(gelu(acc + bias[n]))        (ldc = N)
//   ROLL: A is xb [8192x512]; K=1536 spans segs {t, t-1, t+1} of 512 each
// MODE 1: nv = x[row*ldc+n] + (acc + bias[n]) * cw[row] * 0.3; x=nv; out_bf(xb)=bf16(nv)
template <int MODE, int ROLL>
__global__ __launch_bounds__(256) void gemm_bt(
    const bf16_t* __restrict__ A, int lda,
    const bf16_t* __restrict__ B, int ldb, int K,
    const float* __restrict__ bias,
    bf16_t* __restrict__ out_bf, int ldc,
    const float* __restrict__ cw, float* __restrict__ x)
{
    __shared__ __align__(16) bf16_t As[2 * 128 * 32];
    __shared__ __align__(16) bf16_t Bs[2 * 128 * 32];
    const int tid = threadIdx.x;
    const int m0 = blockIdx.x * 128;
    const int n0 = blockIdx.y * 128;
    const int wave = tid >> 6, lane = tid & 63;
    const int wm = (wave >> 1) * 64, wn = (wave & 1) * 64;
    const int lr = lane & 15, kq = lane >> 4;

    f32x4_t acc[4][4] = {};

    const int srow = tid >> 2;              // 0..63
    const int scol = (tid & 3) * 8;         // bf16 elems
    const bf16_t* gA = A + (size_t)(m0 + srow) * lda + scol;
    const bf16_t* gB = B + (size_t)(n0 + srow) * ldb + scol;
    const size_t a64 = (size_t)64 * lda, b64 = (size_t)64 * ldb;

    auto stage = [&](int k0, int c) {
        bf16_t* lA = &As[c * 4096 + srow * 32 + scol];
        bf16_t* lB = &Bs[c * 4096 + srow * 32 + scol];
        if (ROLL) {
            const int seg = k0 >> 9;
            const int kk = k0 & 511;
            const int sh = (seg == 0) ? 0 : ((seg == 1) ? 1023 : 1);
            const int r1 = m0 + srow;
            const int r2 = r1 + 64;
            const bf16_t* g1 = A + (size_t)((r1 & ~1023) | (((r1 & 1023) + sh) & 1023)) * 512 + kk + scol;
            const bf16_t* g2 = A + (size_t)((r2 & ~1023) | (((r2 & 1023) + sh) & 1023)) * 512 + kk + scol;
            load_lds16(g1, lA);
            load_lds16(g2, lA + 64 * 32);
        } else {
            load_lds16(gA + k0,       lA);
            load_lds16(gA + k0 + a64, lA + 64 * 32);
        }
        load_lds16(gB + k0,       lB);
        load_lds16(gB + k0 + b64, lB + 64 * 32);
    };
    auto compute = [&](int c) {
        const bf16_t* cA = &As[c * 4096];
        const bf16_t* cB = &Bs[c * 4096];
        bf16x8_t af[4], bfr[4];
        #pragma unroll
        for (int i = 0; i < 4; ++i) {
            af[i]  = *(const bf16x8_t*)&cA[(wm + i * 16 + lr) * 32 + kq * 8];
            bfr[i] = *(const bf16x8_t*)&cB[(wn + i * 16 + lr) * 32 + kq * 8];
        }
        #pragma unroll
        for (int i = 0; i < 4; ++i)
            #pragma unroll
            for (int j = 0; j < 4; ++j)
                acc[i][j] = __builtin_amdgcn_mfma_f32_16x16x32_bf16(af[i], bfr[j], acc[i][j], 0, 0, 0);
    };

    // prologue
    stage(0, 0);
    asm volatile("s_waitcnt vmcnt(0)" ::: "memory");
    __builtin_amdgcn_s_barrier();
    __builtin_amdgcn_sched_barrier(0);

    const int nt = K >> 5;
    int cur = 0;
    for (int t = 0; t < nt - 1; ++t) {
        stage((t + 1) << 5, cur ^ 1);      // prefetch next tile (in flight during MFMA)
        compute(cur);
        __builtin_amdgcn_sched_barrier(0); // pin MFMAs/ds_reads above the waits (rule #18)
        asm volatile("s_waitcnt vmcnt(0) lgkmcnt(0)" ::: "memory");
        __builtin_amdgcn_s_barrier();
        __builtin_amdgcn_sched_barrier(0);
        cur ^= 1;
    }
    compute(cur);

    #pragma unroll
    for (int i = 0; i < 4; ++i) {
        const int rbase = m0 + wm + i * 16 + kq * 4;   // C/D: row=(lane>>4)*4+reg
        #pragma unroll
        for (int j = 0; j < 4; ++j) {
            const int gcol = n0 + wn + j * 16 + lr;    // C/D: col=lane&15
            #pragma unroll
            for (int r = 0; r < 4; ++r) {
                const size_t grow = (size_t)(rbase + r);
                float v = acc[i][j][r];
                if (MODE == 0) {
                    v = gelu_f(v + bias[gcol]);
                    out_bf[grow * ldc + gcol] = __float2bfloat16(v);
                } else {
                    v += bias[gcol];
                    float nv = x[grow * ldc + gcol] + v * cw[grow] * 0.3f;
                    x[grow * ldc + gcol] = nv;
                    out_bf[grow * ldc + gcol] = __float2bfloat16(nv);
                }
            }
        }
    }
}

// ---------------- head GEMM: 256x256 tile, 512 threads, double-buffered ----------------
__global__ __launch_bounds__(512) void gemm_head(
    const bf16_t* __restrict__ A,     // [8192 x 512]
    const bf16_t* __restrict__ B,     // [32000 x 512]
    float* __restrict__ out)          // [8192 x 32000]
{
    __shared__ __align__(16) bf16_t As[2 * 256 * 32];
    __shared__ __align__(16) bf16_t Bs[2 * 256 * 32];
    // bijective XCD-chunked swizzle: nwg = 32*125 = 4000, 4000 % 8 == 0
    const int id = blockIdx.x + blockIdx.y * 32;
    const int nid = (id & 7) * 500 + (id >> 3);
    const int m0 = (nid & 31) * 256;
    const int n0 = (nid >> 5) * 256;

    const int tid = threadIdx.x;
    const int wave = tid >> 6, lane = tid & 63;
    const int wm = (wave >> 2) * 128, wn = (wave & 3) * 64;
    const int lr = lane & 15, kq = lane >> 4;

    f32x4_t acc[8][4] = {};

    const int srow = tid >> 2;              // 0..127
    const int scol = (tid & 3) * 8;
    const bf16_t* gA = A + (size_t)(m0 + srow) * 512 + scol;
    const bf16_t* gB = B + (size_t)(n0 + srow) * 512 + scol;
    const size_t s128 = (size_t)128 * 512;

    auto stage = [&](int k0, int c) {
        bf16_t* lA = &As[c * 8192 + srow * 32 + scol];
        bf16_t* lB = &Bs[c * 8192 + srow * 32 + scol];
        load_lds16(gA + k0,        lA);
        load_lds16(gA + k0 + s128, lA + 128 * 32);
        load_lds16(gB + k0,        lB);
        load_lds16(gB + k0 + s128, lB + 128 * 32);
    };
    auto compute = [&](int c) {
        const bf16_t* cA = &As[c * 8192];
        const bf16_t* cB = &Bs[c * 8192];
        bf16x8_t af[8], bfr[4];
        #pragma unroll
        for (int i = 0; i < 8; ++i)
            af[i]  = *(const bf16x8_t*)&cA[(wm + i * 16 + lr) * 32 + kq * 8];
        #pragma unroll
        for (int j = 0; j < 4; ++j)
            bfr[j] = *(const bf16x8_t*)&cB[(wn + j * 16 + lr) * 32 + kq * 8];
        #pragma unroll
        for (int i = 0; i < 8; ++i)
            #pragma unroll
            for (int j = 0; j < 4; ++j)
                acc[i][j] = __builtin_amdgcn_mfma_f32_16x16x32_bf16(af[i], bfr[j], acc[i][j], 0, 0, 0);
    };

    stage(0, 0);
    asm volatile("s_waitcnt vmcnt(0)" ::: "memory");
    __builtin_amdgcn_s_barrier();
    __builtin_amdgcn_sched_barrier(0);

    int cur = 0;
    for (int t = 0; t < 15; ++t) {
        stage((t + 1) << 5, cur ^ 1);
        compute(cur);
        __builtin_amdgcn_sched_barrier(0);
        asm volatile("s_waitcnt vmcnt(0) lgkmcnt(0)" ::: "memory");
        __builtin_amdgcn_s_barrier();
        __builtin_amdgcn_sched_barrier(0);
        cur ^= 1;
    }
    compute(cur);

    #pragma unroll
    for (int i = 0; i < 8; ++i) {
        const int rbase = m0 + wm + i * 16 + kq * 4;
        #pragma unroll
        for (int j = 0; j < 4; ++j) {
            const int gcol = n0 + wn + j * 16 + lr;
            #pragma unroll
            for (int r = 0; r < 4; ++r)
                out[(size_t)(rbase + r) * 32000 + gcol] = acc[i][j][r];
        }
    }
}

extern "C" void kernel_launch(void* const* d_in, const int* in_sizes, int n_in,
                              void* d_out, int out_size, void* d_ws, size_t ws_size,
                              hipStream_t stream) {
    const int*   tokens   = (const int*)d_in[0];
    const float* c_states = (const float*)d_in[1];
    const float* embed_w  = (const float*)d_in[2];
    const float* pos_w    = (const float*)d_in[3];
    const float* cn_w1    = (const float*)d_in[4];
    const float* cn_b1    = (const float*)d_in[5];
    const float* cn_w2    = (const float*)d_in[6];
    const float* cn_b2    = (const float*)d_in[7];
    const float* ent_w1   = (const float*)d_in[8];
    const float* ent_b1   = (const float*)d_in[9];
    const float* ent_w2   = (const float*)d_in[10];
    const float* ent_b2   = (const float*)d_in[11];
    const float* ctc_w1   = (const float*)d_in[12];
    const float* ctc_b1   = (const float*)d_in[13];
    const float* ctc_w2   = (const float*)d_in[14];
    const float* ctc_b2   = (const float*)d_in[15];
    const float* base_temp= (const float*)d_in[16];
    const float* ln_g     = (const float*)d_in[17];
    const float* ln_b     = (const float*)d_in[18];
    const float* head_w   = (const float*)d_in[19];
    float* out = (float*)d_out;

    char* ws = (char*)d_ws;
    float*  x     = (float*)(ws + OFF_X);
    bf16_t* xb    = (bf16_t*)(ws + OFF_XB);
    bf16_t* h1    = (bf16_t*)(ws + OFF_H1);
    bf16_t* xn    = (bf16_t*)(ws + OFF_XN);
    bf16_t* headb = (bf16_t*)(ws + OFF_HEADB);
    bf16_t* w1b   = (bf16_t*)(ws + OFF_W1B);
    bf16_t* w2b   = (bf16_t*)(ws + OFF_W2B);
    bf16_t* ew1b  = (bf16_t*)(ws + OFF_EW1);
    float*  ent   = (float*)(ws + OFF_ENT);
    float*  cw    = (float*)(ws + OFF_CW);
    float*  hc    = (float*)(ws + OFF_HC);
    float*  cc    = (float*)(ws + OFF_CC);
    float*  bias1 = (float*)(ws + OFF_B1);

    // weight converts + constant path
    cvt_w1_kernel<<<1536, 256, 0, stream>>>(cn_w1, w1b);               // 1024*384 quads
    cvt_kernel<<<512, 256, 0, stream>>>(cn_w2, w2b);                   // 512*1024/4
    cvt_kernel<<<32, 256, 0, stream>>>(ent_w1, ew1b);                  // 64*512/4
    prep1_kernel<<<4, 256, 0, stream>>>(c_states, ctc_w1, ctc_b1, hc);
    prep2_kernel<<<2, 256, 0, stream>>>(hc, ctc_w2, ctc_b2, cc);
    prep3_kernel<<<4, 256, 0, stream>>>(cc, cn_w1, cn_b1, bias1);
    embed_kernel<<<4096, 256, 0, stream>>>(tokens, embed_w, pos_w, x, xb);

    for (int step = 0; step < 6; ++step) {
        float stepf = 1.0f - ((float)step / 6.0f) * 0.8f;
        entropy_mfma<<<128, 256, 0, stream>>>(xb, ew1b, ent_b1, ent_w2, ent_b2, ent);
        softmax_kernel<<<8, 1024, 0, stream>>>(ent, base_temp, stepf, cw);
        gemm_bt<0, 1><<<dim3(64, 8), 256, 0, stream>>>(xb, 512, w1b, 1536, 1536,
                                                       bias1, h1, 1024, nullptr, nullptr);
        gemm_bt<1, 0><<<dim3(64, 4), 256, 0, stream>>>(h1, 1024, w2b, 1024, 1024,
                                                       cn_b2, xb, 512, cw, x);
    }

    cvt_kernel<<<16000, 256, 0, stream>>>(head_w, headb);              // 32000*512/4
    ln_kernel<<<2048, 256, 0, stream>>>(x, ln_g, ln_b, xn);
    gemm_head<<<dim3(32, 125), 512, 0, stream>>>(xn, headb, out);
}

// Round 4
// 1204.849 us; speedup vs baseline: 1.6801x; 1.0780x over previous
//
#include <hip/hip_runtime.h>
#include <hip/hip_bf16.h>

typedef __hip_bfloat16 bf16_t;
typedef __bf16 bf16x8_t __attribute__((ext_vector_type(8)));
typedef float f32x4_t __attribute__((ext_vector_type(4)));

// ---------------- workspace layout (bytes) ----------------
#define OFF_X     ((size_t)0)          // 8192*512  f32  = 16,777,216
#define OFF_XB    ((size_t)16777216)   // 8192*512  bf16 =  8,388,608
#define OFF_H1    ((size_t)25165824)   // 8192*1024 bf16 = 16,777,216
#define OFF_XN    ((size_t)41943040)   // 8192*512  bf16 =  8,388,608
#define OFF_HEADB ((size_t)50331648)   // 32000*512 bf16 = 32,768,000
#define OFF_W1B   ((size_t)83099648)   // 1024*1536 bf16 =  3,145,728
#define OFF_W2B   ((size_t)86245376)   // 512*1024  bf16 =  1,048,576
#define OFF_EW1   ((size_t)87293952)   // 64*512    bf16 =     65,536
#define OFF_ENT   ((size_t)87359488)   // 8192 f32
#define OFF_CW    ((size_t)87392256)   // 8192 f32
#define OFF_HC    ((size_t)87425024)   // 1024 f32
#define OFF_CC    ((size_t)87429120)   // 512  f32
#define OFF_B1    ((size_t)87431168)   // 1024 f32

__device__ __forceinline__ float gelu_f(float v) {
    return 0.5f * v * (1.0f + erff(v * 0.7071067811865475f));
}

__device__ __forceinline__ void load_lds16(const bf16_t* g, bf16_t* l) {
    __builtin_amdgcn_global_load_lds(
        (const __attribute__((address_space(1))) void*)g,
        (__attribute__((address_space(3))) void*)l, 16, 0, 0);
}

#define BAR()    __builtin_amdgcn_s_barrier()
#define SCHED0() __builtin_amdgcn_sched_barrier(0)
#define LGKM0()  asm volatile("s_waitcnt lgkmcnt(0)" ::: "memory")
#define WAITV0() asm volatile("s_waitcnt vmcnt(0)" ::: "memory")
#define WAITV2() asm volatile("s_waitcnt vmcnt(2)" ::: "memory")
#define WAITV4() asm volatile("s_waitcnt vmcnt(4)" ::: "memory")

// ---------------- prep: ctc MLP on pooled c_states, fold into bias1 ----------------
__global__ void prep1_kernel(const float* __restrict__ cs, const float* __restrict__ w1,
                             const float* __restrict__ b1, float* __restrict__ hc) {
    int o = blockIdx.x * 256 + threadIdx.x;            // 0..1023
    const float* wr = w1 + (size_t)o * 512;
    float acc = 0.f;
    for (int k = 0; k < 512; k += 4) {
        float4 w4 = *(const float4*)(wr + k);
        float4 a = *(const float4*)(cs + k);
        float4 b = *(const float4*)(cs + 512 + k);
        float4 c = *(const float4*)(cs + 1024 + k);
        float4 d = *(const float4*)(cs + 1536 + k);
        acc += w4.x * (a.x + b.x + c.x + d.x) * 0.25f;
        acc += w4.y * (a.y + b.y + c.y + d.y) * 0.25f;
        acc += w4.z * (a.z + b.z + c.z + d.z) * 0.25f;
        acc += w4.w * (a.w + b.w + c.w + d.w) * 0.25f;
    }
    hc[o] = gelu_f(acc + b1[o]);
}

__global__ void prep2_kernel(const float* __restrict__ hc, const float* __restrict__ w2,
                             const float* __restrict__ b2, float* __restrict__ cc) {
    int o = blockIdx.x * 256 + threadIdx.x;            // 0..511
    const float* wr = w2 + (size_t)o * 1024;
    float acc = 0.f;
    for (int k = 0; k < 1024; ++k) acc += wr[k] * hc[k];
    cc[o] = acc + b2[o];
}

__global__ void prep3_kernel(const float* __restrict__ cc, const float* __restrict__ cn_w1,
                             const float* __restrict__ cn_b1, float* __restrict__ bias1) {
    int o = blockIdx.x * 256 + threadIdx.x;            // 0..1023
    const float* wr = cn_w1 + (size_t)o * 2048 + 1536;
    float acc = 0.f;
    for (int k = 0; k < 512; ++k) acc += wr[k] * cc[k];
    bias1[o] = acc + cn_b1[o];
}

// ---------------- embed + pos -> x (f32) and xb (bf16) ----------------
__global__ void embed_kernel(const int* __restrict__ tokens, const float* __restrict__ ew,
                             const float* __restrict__ pw, float* __restrict__ x,
                             bf16_t* __restrict__ xb) {
    int idx = blockIdx.x * 256 + threadIdx.x;          // quad id, total 8192*128
    int d4 = idx & 127;
    int bt = idx >> 7;
    int t = bt & 1023;
    int tok = tokens[bt];
    float4 e = ((const float4*)(ew + (size_t)tok * 512))[d4];
    float4 p = ((const float4*)(pw + (size_t)t * 512))[d4];
    float4 o = make_float4(e.x + p.x, e.y + p.y, e.z + p.z, e.w + p.w);
    ((float4*)x)[idx] = o;
    __hip_bfloat162 p0, p1;
    p0.x = __float2bfloat16(o.x); p0.y = __float2bfloat16(o.y);
    p1.x = __float2bfloat16(o.z); p1.y = __float2bfloat16(o.w);
    ((__hip_bfloat162*)xb)[idx * 2]     = p0;
    ((__hip_bfloat162*)xb)[idx * 2 + 1] = p1;
}

// ---------------- f32 -> bf16 converts ----------------
__global__ void cvt_kernel(const float* __restrict__ src, bf16_t* __restrict__ dst) {
    int idx = blockIdx.x * 256 + threadIdx.x;          // quad id, grid sized exactly
    float4 v = ((const float4*)src)[idx];
    __hip_bfloat162 p0, p1;
    p0.x = __float2bfloat16(v.x); p0.y = __float2bfloat16(v.y);
    p1.x = __float2bfloat16(v.z); p1.y = __float2bfloat16(v.w);
    ((__hip_bfloat162*)dst)[idx * 2]     = p0;
    ((__hip_bfloat162*)dst)[idx * 2 + 1] = p1;
}

__global__ void cvt_w1_kernel(const float* __restrict__ w1, bf16_t* __restrict__ dst) {
    int idx = blockIdx.x * 256 + threadIdx.x;          // quad id, total 1024*384
    int k4 = idx % 384;
    int o = idx / 384;
    float4 v = ((const float4*)(w1 + (size_t)o * 2048))[k4];
    __hip_bfloat162 p0, p1;
    p0.x = __float2bfloat16(v.x); p0.y = __float2bfloat16(v.y);
    p1.x = __float2bfloat16(v.z); p1.y = __float2bfloat16(v.w);
    ((__hip_bfloat162*)dst)[idx * 2]     = p0;
    ((__hip_bfloat162*)dst)[idx * 2 + 1] = p1;
}

// ---------------- entropy MLP via MFMA: 16 tokens per wave ----------------
__global__ __launch_bounds__(256) void entropy_mfma(
        const bf16_t* __restrict__ xb, const bf16_t* __restrict__ w1b,
        const float* __restrict__ b1, const float* __restrict__ w2,
        const float* __restrict__ b2, float* __restrict__ ent) {
    int wave = threadIdx.x >> 6, lane = threadIdx.x & 63;
    int lr = lane & 15, kq = lane >> 4;
    int tok0 = (blockIdx.x * 4 + wave) * 16;
    f32x4_t acc[4] = {};
    const bf16_t* xr = xb + (size_t)(tok0 + lr) * 512 + kq * 8;
    const bf16_t* wr = w1b + (size_t)lr * 512 + kq * 8;
    #pragma unroll 4
    for (int k0 = 0; k0 < 512; k0 += 32) {
        bf16x8_t a = *(const bf16x8_t*)(xr + k0);
        #pragma unroll
        for (int j = 0; j < 4; ++j) {
            bf16x8_t bb = *(const bf16x8_t*)(wr + (size_t)j * 16 * 512 + k0);
            acc[j] = __builtin_amdgcn_mfma_f32_16x16x32_bf16(a, bb, acc[j], 0, 0, 0);
        }
    }
    float p[4];
    #pragma unroll
    for (int r = 0; r < 4; ++r) {
        float s = 0.f;
        #pragma unroll
        for (int j = 0; j < 4; ++j) {
            int n = j * 16 + lr;
            s += gelu_f(acc[j][r] + b1[n]) * w2[n];
        }
        #pragma unroll
        for (int o = 1; o < 16; o <<= 1) s += __shfl_xor(s, o);
        p[r] = s;
    }
    if (lr == 0) {
        float bb = b2[0];
        #pragma unroll
        for (int r = 0; r < 4; ++r) ent[tok0 + kq * 4 + r] = p[r] + bb;
    }
}

// ---------------- softmax over T (per batch) ----------------
__global__ void softmax_kernel(const float* __restrict__ ent, const float* __restrict__ btp,
                               float stepf, float* __restrict__ cw) {
    __shared__ float red[16];
    __shared__ float bc[2];
    int b = blockIdx.x, t = threadIdx.x;               // 1024 threads
    float bt = btp[0];
    float sp = (bt > 20.0f) ? bt : log1pf(expf(bt));
    float inv = -1.0f / (sp * stepf);
    float v = ent[b * 1024 + t] * inv;
    float m = v;
    #pragma unroll
    for (int o = 32; o; o >>= 1) m = fmaxf(m, __shfl_xor(m, o));
    if ((t & 63) == 0) red[t >> 6] = m;
    __syncthreads();
    if (t < 64) {
        float mm = (t < 16) ? red[t] : -3.4e38f;
        #pragma unroll
        for (int o = 32; o; o >>= 1) mm = fmaxf(mm, __shfl_xor(mm, o));
        if (t == 0) bc[0] = mm;
    }
    __syncthreads();
    float e = expf(v - bc[0]);
    float s = e;
    #pragma unroll
    for (int o = 32; o; o >>= 1) s += __shfl_xor(s, o);
    if ((t & 63) == 0) red[t >> 6] = s;
    __syncthreads();
    if (t < 64) {
        float ss = (t < 16) ? red[t] : 0.f;
        #pragma unroll
        for (int o = 32; o; o >>= 1) ss += __shfl_xor(ss, o);
        if (t == 0) bc[1] = ss;
    }
    __syncthreads();
    cw[b * 1024 + t] = e / bc[1];
}

// ---------------- LayerNorm -> bf16 (one wave per token) ----------------
__global__ void ln_kernel(const float* __restrict__ x, const float* __restrict__ g,
                          const float* __restrict__ b, bf16_t* __restrict__ xn) {
    int token = blockIdx.x * 4 + (threadIdx.x >> 6);
    int l = threadIdx.x & 63;
    const float* xr = x + (size_t)token * 512;
    float4 v0 = ((const float4*)xr)[l * 2];
    float4 v1 = ((const float4*)xr)[l * 2 + 1];
    float s = v0.x + v0.y + v0.z + v0.w + v1.x + v1.y + v1.z + v1.w;
    float ss = v0.x * v0.x + v0.y * v0.y + v0.z * v0.z + v0.w * v0.w
             + v1.x * v1.x + v1.y * v1.y + v1.z * v1.z + v1.w * v1.w;
    #pragma unroll
    for (int o = 32; o; o >>= 1) { s += __shfl_xor(s, o); ss += __shfl_xor(ss, o); }
    float mu = s * (1.0f / 512.0f);
    float var = ss * (1.0f / 512.0f) - mu * mu;
    float rs = rsqrtf(var + 1e-5f);
    float4 g0 = ((const float4*)g)[l * 2], g1 = ((const float4*)g)[l * 2 + 1];
    float4 b0 = ((const float4*)b)[l * 2], b1 = ((const float4*)b)[l * 2 + 1];
    bf16_t* op = xn + (size_t)token * 512 + l * 8;
    op[0] = __float2bfloat16((v0.x - mu) * rs * g0.x + b0.x);
    op[1] = __float2bfloat16((v0.y - mu) * rs * g0.y + b0.y);
    op[2] = __float2bfloat16((v0.z - mu) * rs * g0.z + b0.z);
    op[3] = __float2bfloat16((v0.w - mu) * rs * g0.w + b0.w);
    op[4] = __float2bfloat16((v1.x - mu) * rs * g1.x + b1.x);
    op[5] = __float2bfloat16((v1.y - mu) * rs * g1.y + b1.y);
    op[6] = __float2bfloat16((v1.z - mu) * rs * g1.z + b1.z);
    op[7] = __float2bfloat16((v1.w - mu) * rs * g1.w + b1.w);
}

// ================= 8-phase 256xBN bf16 MFMA GEMM (m201 template, plain HIP) ========
// C = A[M,K] @ B[N,K]^T.  512 threads = 8 waves (2M x 4N), BK=64, per-wave 128 x BN/4.
// LDS XOR-swizzle on 16B units (ku ^= row&7): linear gload_lds dest + pre-swizzled
// global source + swizzled ds_read (rule #21).
// Staging: p0/p1 -> A halves of tile t+1 (buf^1); p2/p3 -> B halves of tile t+2
// (into buf: B region is register-resident after phase 0). Boundary wait vmcnt(VN).
// MODE 0: out_bf = bf16(gelu(acc+bias[n]))            (ROLL staging of A = xb)
// MODE 1: nv = x[..]+ (acc+bias[n])*cw[row]*0.3; x=nv; out_bf = bf16(nv)
// MODE 2: out_f = acc
template <int MODE, int ROLL, int BN>
__global__ __launch_bounds__(512, 2) void gemm8p(
    const bf16_t* __restrict__ A, int lda,
    const bf16_t* __restrict__ B, int ldb, int K, int NMT,
    const float* __restrict__ bias,
    bf16_t* __restrict__ out_bf, int ldc,
    const float* __restrict__ cw, float* __restrict__ x,
    float* __restrict__ out_f)
{
    constexpr int JJ = BN / 64;                 // B-frags per wave per kk (4 or 2)
    __shared__ __align__(16) bf16_t As[2][256 * 64];
    __shared__ __align__(16) bf16_t Bs[2][BN * 64];

    const int NT = K >> 6;
    const int nwg = gridDim.x;
    const int id0 = blockIdx.x;
    const int id = (id0 & 7) * (nwg >> 3) + (id0 >> 3);   // bijective XCD swizzle (nwg%8==0)
    const int m0 = (id % NMT) * 256;
    const int n0 = (id / NMT) * BN;

    const int tid = threadIdx.x;
    const int wave = tid >> 6, lane = tid & 63;
    const int wm = (wave >> 2) * 128;
    const int wn = (wave & 3) * (BN / 4);
    const int lr = lane & 15, kq = lane >> 4;

    // ds_read element offsets: logical (row, ku) lives at elem row*64 + (ku^(row&7))*8.
    // row & 7 == lr & 7 for all fragment reads.
    const int swz0 = (kq)     ^ (lr & 7);       // kk=0: ku = kq
    const int swz1 = (4 + kq) ^ (lr & 7);       // kk=1: ku = 4+kq
    const int eoff0 = lr * 64 + swz0 * 8;
    const int eoff1 = lr * 64 + swz1 * 8;

    // staging: thread handles 16B units u0=tid, u1=tid+512 of a 128x64 half-tile
    const int u0row = tid >> 3;                 // 0..63
    const int u1row = 64 + (tid >> 3);          // 64..127
    const int usl   = tid & 7;
    const int c0 = ((usl ^ (u0row & 7)) * 8);   // source elem col (pre-swizzled)
    const int c1 = ((usl ^ (u1row & 7)) * 8);

    f32x4_t acc[8][JJ] = {};
    bf16x8_t bfr[JJ][2];

    auto stageA = [&](int ktile, int c, int half) {
        const int kbase = ktile << 6;
        const int r0 = m0 + half * 128 + u0row;
        const int r1 = m0 + half * 128 + u1row;
        const bf16_t *g0, *g1;
        if (ROLL) {
            const int seg = kbase >> 9;
            const int kk2 = kbase & 511;
            const int sh = (seg == 0) ? 0 : ((seg == 1) ? 1023 : 1);
            const int s0 = (r0 & ~1023) | (((r0 & 1023) + sh) & 1023);
            const int s1 = (r1 & ~1023) | (((r1 & 1023) + sh) & 1023);
            g0 = A + (size_t)s0 * 512 + kk2 + c0;
            g1 = A + (size_t)s1 * 512 + kk2 + c1;
        } else {
            g0 = A + (size_t)r0 * lda + kbase + c0;
            g1 = A + (size_t)r1 * lda + kbase + c1;
        }
        bf16_t* l = &As[c][half * 128 * 64];
        load_lds16(g0, l + tid * 8);
        load_lds16(g1, l + (tid + 512) * 8);
    };
    auto stageB = [&](int ktile, int c, int half) {
        const int kbase = ktile << 6;
        const int r0 = n0 + half * 128 + u0row;
        const int r1 = n0 + half * 128 + u1row;
        const bf16_t* g0 = B + (size_t)r0 * ldb + kbase + c0;
        const bf16_t* g1 = B + (size_t)r1 * ldb + kbase + c1;
        bf16_t* l = &Bs[c][half * 128 * 64];
        load_lds16(g0, l + tid * 8);
        load_lds16(g1, l + (tid + 512) * 8);
    };

    // ---- prologue: A(0), B(0) resident; B(1) in flight ----
    stageA(0, 0, 0); stageA(0, 0, 1);
    stageB(0, 0, 0); if (BN == 256) stageB(0, 0, 1);
    stageB(1, 1, 0); if (BN == 256) stageB(1, 1, 1);
    if (BN == 256) { WAITV4(); } else { WAITV2(); }
    BAR();

    int cur = 0;
    for (int t = 0; t < NT; ++t) {
        #pragma unroll
        for (int p = 0; p < 4; ++p) {
            // ds-read this phase's A frags (+ all B frags at p==0)
            bf16x8_t af0k0, af0k1, af1k0, af1k1;
            {
                const int r0 = (wm + 32 * p + lr) * 64;
                const int r1 = (wm + 32 * p + 16 + lr) * 64;
                af0k0 = *(const bf16x8_t*)&As[cur][r0 - lr * 64 + eoff0];
                af0k1 = *(const bf16x8_t*)&As[cur][r0 - lr * 64 + eoff1];
                af1k0 = *(const bf16x8_t*)&As[cur][r1 - lr * 64 + eoff0];
                af1k1 = *(const bf16x8_t*)&As[cur][r1 - lr * 64 + eoff1];
            }
            if (p == 0) {
                #pragma unroll
                for (int j = 0; j < JJ; ++j) {
                    const int rb = (wn + 16 * j) * 64;
                    bfr[j][0] = *(const bf16x8_t*)&Bs[cur][rb + eoff0];
                    bfr[j][1] = *(const bf16x8_t*)&Bs[cur][rb + eoff1];
                }
            }
            // stage (2 x global_load_lds)
            if (p == 0 && t + 1 < NT) stageA(t + 1, cur ^ 1, 0);
            if (p == 1 && t + 1 < NT) stageA(t + 1, cur ^ 1, 1);
            if (p == 2 && t + 2 < NT) stageB(t + 2, cur, 0);
            if (p == 3 && BN == 256 && t + 2 < NT) stageB(t + 2, cur, 1);

            BAR();
            LGKM0();
            SCHED0();
            __builtin_amdgcn_s_setprio(1);
            #pragma unroll
            for (int j = 0; j < JJ; ++j) {
                acc[2*p][j]   = __builtin_amdgcn_mfma_f32_16x16x32_bf16(af0k0, bfr[j][0], acc[2*p][j],   0, 0, 0);
                acc[2*p+1][j] = __builtin_amdgcn_mfma_f32_16x16x32_bf16(af1k0, bfr[j][0], acc[2*p+1][j], 0, 0, 0);
            }
            #pragma unroll
            for (int j = 0; j < JJ; ++j) {
                acc[2*p][j]   = __builtin_amdgcn_mfma_f32_16x16x32_bf16(af0k1, bfr[j][1], acc[2*p][j],   0, 0, 0);
                acc[2*p+1][j] = __builtin_amdgcn_mfma_f32_16x16x32_bf16(af1k1, bfr[j][1], acc[2*p+1][j], 0, 0, 0);
            }
            __builtin_amdgcn_s_setprio(0);
            SCHED0();
            if (p == 3) {
                if (t + 2 < NT) { if (BN == 256) { WAITV4(); } else { WAITV2(); } }
                else           { WAITV0(); }
            }
            BAR();
        }
        cur ^= 1;
    }

    // ---- epilogue ----
    #pragma unroll
    for (int i = 0; i < 8; ++i) {
        const int rbase = m0 + wm + i * 16 + kq * 4;   // C/D: row=(lane>>4)*4+reg
        #pragma unroll
        for (int j = 0; j < JJ; ++j) {
            const int gcol = n0 + wn + j * 16 + lr;    // C/D: col=lane&15
            #pragma unroll
            for (int r = 0; r < 4; ++r) {
                const size_t grow = (size_t)(rbase + r);
                float v = acc[i][j][r];
                if (MODE == 0) {
                    v = gelu_f(v + bias[gcol]);
                    out_bf[grow * ldc + gcol] = __float2bfloat16(v);
                } else if (MODE == 1) {
                    v += bias[gcol];
                    float nv = x[grow * ldc + gcol] + v * cw[grow] * 0.3f;
                    x[grow * ldc + gcol] = nv;
                    out_bf[grow * ldc + gcol] = __float2bfloat16(nv);
                } else {
                    out_f[grow * ldc + gcol] = v;
                }
            }
        }
    }
}

extern "C" void kernel_launch(void* const* d_in, const int* in_sizes, int n_in,
                              void* d_out, int out_size, void* d_ws, size_t ws_size,
                              hipStream_t stream) {
    const int*   tokens   = (const int*)d_in[0];
    const float* c_states = (const float*)d_in[1];
    const float* embed_w  = (const float*)d_in[2];
    const float* pos_w    = (const float*)d_in[3];
    const float* cn_w1    = (const float*)d_in[4];
    const float* cn_b1    = (const float*)d_in[5];
    const float* cn_w2    = (const float*)d_in[6];
    const float* cn_b2    = (const float*)d_in[7];
    const float* ent_w1   = (const float*)d_in[8];
    const float* ent_b1   = (const float*)d_in[9];
    const float* ent_w2   = (const float*)d_in[10];
    const float* ent_b2   = (const float*)d_in[11];
    const float* ctc_w1   = (const float*)d_in[12];
    const float* ctc_b1   = (const float*)d_in[13];
    const float* ctc_w2   = (const float*)d_in[14];
    const float* ctc_b2   = (const float*)d_in[15];
    const float* base_temp= (const float*)d_in[16];
    const float* ln_g     = (const float*)d_in[17];
    const float* ln_b     = (const float*)d_in[18];
    const float* head_w   = (const float*)d_in[19];
    float* out = (float*)d_out;

    char* ws = (char*)d_ws;
    float*  x     = (float*)(ws + OFF_X);
    bf16_t* xb    = (bf16_t*)(ws + OFF_XB);
    bf16_t* h1    = (bf16_t*)(ws + OFF_H1);
    bf16_t* xn    = (bf16_t*)(ws + OFF_XN);
    bf16_t* headb = (bf16_t*)(ws + OFF_HEADB);
    bf16_t* w1b   = (bf16_t*)(ws + OFF_W1B);
    bf16_t* w2b   = (bf16_t*)(ws + OFF_W2B);
    bf16_t* ew1b  = (bf16_t*)(ws + OFF_EW1);
    float*  ent   = (float*)(ws + OFF_ENT);
    float*  cw    = (float*)(ws + OFF_CW);
    float*  hc    = (float*)(ws + OFF_HC);
    float*  cc    = (float*)(ws + OFF_CC);
    float*  bias1 = (float*)(ws + OFF_B1);

    // weight converts + constant path
    cvt_w1_kernel<<<1536, 256, 0, stream>>>(cn_w1, w1b);               // 1024*384 quads
    cvt_kernel<<<512, 256, 0, stream>>>(cn_w2, w2b);                   // 512*1024/4
    cvt_kernel<<<32, 256, 0, stream>>>(ent_w1, ew1b);                  // 64*512/4
    prep1_kernel<<<4, 256, 0, stream>>>(c_states, ctc_w1, ctc_b1, hc);
    prep2_kernel<<<2, 256, 0, stream>>>(hc, ctc_w2, ctc_b2, cc);
    prep3_kernel<<<4, 256, 0, stream>>>(cc, cn_w1, cn_b1, bias1);
    embed_kernel<<<4096, 256, 0, stream>>>(tokens, embed_w, pos_w, x, xb);

    for (int step = 0; step < 6; ++step) {
        float stepf = 1.0f - ((float)step / 6.0f) * 0.8f;
        entropy_mfma<<<128, 256, 0, stream>>>(xb, ew1b, ent_b1, ent_w2, ent_b2, ent);
        softmax_kernel<<<8, 1024, 0, stream>>>(ent, base_temp, stepf, cw);
        // gemm1: [8192x1536]x[1024x1536]^T, 256x128 tiles -> 32*8=256 blocks
        gemm8p<0, 1, 128><<<256, 512, 0, stream>>>(xb, 512, w1b, 1536, 1536, 32,
                                                   bias1, h1, 1024, nullptr, nullptr, nullptr);
        // gemm2: [8192x1024]x[512x1024]^T, 256x128 tiles -> 32*4=128 blocks
        gemm8p<1, 0, 128><<<128, 512, 0, stream>>>(h1, 1024, w2b, 1024, 1024, 32,
                                                   cn_b2, xb, 512, cw, x, nullptr);
    }

    cvt_kernel<<<16000, 256, 0, stream>>>(head_w, headb);              // 32000*512/4
    ln_kernel<<<2048, 256, 0, stream>>>(x, ln_g, ln_b, xn);
    // head: [8192x512]x[32000x512]^T, 256x256 tiles -> 32*125=4000 blocks
    gemm8p<2, 0, 256><<<4000, 512, 0, stream>>>(xn, 512, headb, 512, 512, 32,
                                                nullptr, nullptr, 32000, nullptr, nullptr, out);
}